// Round 1
// baseline (507.318 us; speedup 1.0000x reference)
//
#include <hip/hip_runtime.h>
#include <hip/hip_bf16.h>
#include <stdint.h>

#define BATCH 8192
#define DIM   2048
#define NEXP  8
#define BM    128
#define BN    128
#define BK    32
#define MAX_TILES 72

typedef __bf16 bf16x8 __attribute__((ext_vector_type(8)));
typedef float  f32x4  __attribute__((ext_vector_type(4)));

// ---- workspace layout (int offsets unless noted) ----
// counts   @ int 0    (8)
// cursor   @ int 16   (8)
// seg_start@ int 32   (8)
// ntiles   @ int 48
// tileExp  @ int 64   (96)
// tilePos0 @ int 160  (96)
// tileVal  @ int 256  (96)
// rowmap   @ int 512  (9216)
// xg  (bf16) @ byte 40960      : 9216*2048*2 = 37,748,736 B
// Wb  (bf16) @ byte 37,789,696 : 8*2048*2048*2 = 67,108,864 B
// total need = 104,898,560 B
#define XG_BYTE_OFF 40960ull
#define WB_BYTE_OFF 37789696ull
#define WS_NEED     104898560ull

#define AS1(p) ((const __attribute__((address_space(1))) void*)(p))
#define AS3(p) ((__attribute__((address_space(3))) void*)(p))

__device__ __forceinline__ unsigned f2bf2(float lo, float hi) {
    unsigned ul = __float_as_uint(lo), uh = __float_as_uint(hi);
    ul = (ul + 0x7FFFu + ((ul >> 16) & 1u)) >> 16;   // RNE
    uh = (uh + 0x7FFFu + ((uh >> 16) & 1u)) >> 16;
    return (uh << 16) | ul;
}

__global__ void k_init(int* ws) {
    int t = threadIdx.x;
    if (t < 512) ws[t] = 0;
}

__global__ void k_hist(const int* __restrict__ ids, int* __restrict__ ws) {
    int i = blockIdx.x * blockDim.x + threadIdx.x;
    if (i < BATCH) atomicAdd(&ws[ids[i]], 1);
}

__global__ void k_plan(int* ws) {
    int* counts = ws;
    int* seg    = ws + 32;
    int* te     = ws + 64;
    int* tp     = ws + 160;
    int* tv     = ws + 256;
    int pos = 0, mt = 0;
    for (int e = 0; e < NEXP; e++) {
        seg[e] = pos;
        int c = counts[e];
        int ntl = (c + BM - 1) / BM;
        for (int t = 0; t < ntl; t++) {
            te[mt] = e;
            tp[mt] = pos + t * BM;
            int v = c - t * BM;
            tv[mt] = v < BM ? v : BM;
            mt++;
        }
        pos += ntl * BM;
    }
    ws[48] = mt;
}

// zero the padding rows of each expert segment in xg
__global__ void k_zeropad(const int* __restrict__ ws, unsigned short* __restrict__ xg) {
    int e = blockIdx.x;
    int c = ws[e];
    int start = ws[32 + e];
    int padded = (c + BM - 1) & ~(BM - 1);
    size_t n16 = (size_t)(padded - c) * (DIM * 2 / 16); // # of uint4
    uint4* p = (uint4*)(xg + (size_t)(start + c) * DIM);
    uint4 z = make_uint4(0, 0, 0, 0);
    for (size_t i = threadIdx.x; i < n16; i += blockDim.x) p[i] = z;
}

// fp32 W -> bf16, 8 elems/thread
__global__ void k_cvtW(const float4* __restrict__ W, uint4* __restrict__ Wb) {
    size_t i = (size_t)blockIdx.x * blockDim.x + threadIdx.x;
    float4 a = W[i * 2], b4 = W[i * 2 + 1];
    uint4 o;
    o.x = f2bf2(a.x, a.y);  o.y = f2bf2(a.z, a.w);
    o.z = f2bf2(b4.x, b4.y); o.w = f2bf2(b4.z, b4.w);
    Wb[i] = o;
}

// one block per source row: claim slot, convert+copy row into xg, record rowmap
__global__ void k_gather(const float* __restrict__ x, const int* __restrict__ ids,
                         int* __restrict__ ws, unsigned short* __restrict__ xg,
                         int* __restrict__ rowmap) {
    __shared__ int spos;
    int i = blockIdx.x;
    if (threadIdx.x == 0) {
        int e = ids[i];
        int p = ws[32 + e] + atomicAdd(&ws[16 + e], 1);
        spos = p;
        rowmap[p] = i;
    }
    __syncthreads();
    int pos = spos;
    const float4* xr = (const float4*)(x + (size_t)i * DIM);
    uint4* o = (uint4*)(xg + (size_t)pos * DIM);
    for (int t = threadIdx.x; t < DIM / 8; t += blockDim.x) {
        float4 a = xr[t * 2], b4 = xr[t * 2 + 1];
        uint4 v;
        v.x = f2bf2(a.x, a.y);  v.y = f2bf2(a.z, a.w);
        v.z = f2bf2(b4.x, b4.y); v.w = f2bf2(b4.z, b4.w);
        o[t] = v;
    }
}

// grouped GEMM: C[tile 128x128] = Xg[128xK] * W[e][128 rows of N, K]^T
// m97 structure: global_load_lds(16B) staging, ds_read_b128 frags, 16x16x32 bf16 MFMA
__launch_bounds__(256)
__global__ void k_gemm(const unsigned short* __restrict__ xg,
                       const unsigned short* __restrict__ Wb,
                       const float* __restrict__ x, const float* __restrict__ bias,
                       const int* __restrict__ ws, const int* __restrict__ rowmap,
                       float* __restrict__ out) {
    int mt = blockIdx.y;
    if (mt >= ws[48]) return;
    int e     = ws[64  + mt];
    int pos0  = ws[160 + mt];
    int valid = ws[256 + mt];
    int n0 = blockIdx.x * BN;

    __shared__ unsigned short lA[BM * BK];
    __shared__ unsigned short lB[BN * BK];

    int tid = threadIdx.x;
    int w = tid >> 6, l = tid & 63;
    int lane15 = l & 15, quad = l >> 4;
    int wave_m = (w >> 1) * 64, wave_n = (w & 1) * 64;

    const unsigned short* Abase = xg + (size_t)pos0 * DIM;
    const unsigned short* Bbase = Wb + (size_t)e * DIM * DIM + (size_t)n0 * DIM;

    f32x4 acc[4][4];
    for (int i = 0; i < 4; i++)
        for (int j = 0; j < 4; j++) acc[i][j] = (f32x4){0.f, 0.f, 0.f, 0.f};

    // staging chunks: chunk c covers row=c>>2, k-offset=(c&3)*8 (16B). Wave w
    // stages chunks [w*128, w*128+128) in two issues of 64.
    int c0 = w * 128 + l;
    int c1 = w * 128 + 64 + l;

    for (int k0 = 0; k0 < DIM; k0 += BK) {
        __syncthreads();
        __builtin_amdgcn_global_load_lds(
            AS1(Abase + (size_t)(c0 >> 2) * DIM + k0 + (c0 & 3) * 8),
            AS3(lA + w * 1024), 16, 0, 0);
        __builtin_amdgcn_global_load_lds(
            AS1(Abase + (size_t)(c1 >> 2) * DIM + k0 + (c1 & 3) * 8),
            AS3(lA + w * 1024 + 512), 16, 0, 0);
        __builtin_amdgcn_global_load_lds(
            AS1(Bbase + (size_t)(c0 >> 2) * DIM + k0 + (c0 & 3) * 8),
            AS3(lB + w * 1024), 16, 0, 0);
        __builtin_amdgcn_global_load_lds(
            AS1(Bbase + (size_t)(c1 >> 2) * DIM + k0 + (c1 & 3) * 8),
            AS3(lB + w * 1024 + 512), 16, 0, 0);
        __syncthreads();

        bf16x8 af[4], bf[4];
        for (int mi = 0; mi < 4; mi++)
            af[mi] = *(const bf16x8*)(lA + (wave_m + mi * 16 + lane15) * BK + quad * 8);
        for (int ni = 0; ni < 4; ni++)
            bf[ni] = *(const bf16x8*)(lB + (wave_n + ni * 16 + lane15) * BK + quad * 8);
        for (int mi = 0; mi < 4; mi++)
            for (int ni = 0; ni < 4; ni++)
                acc[mi][ni] = __builtin_amdgcn_mfma_f32_16x16x32_bf16(
                    af[mi], bf[ni], acc[mi][ni], 0, 0, 0);
    }

    // epilogue: bias + relu + residual + scatter back via rowmap
    float bv[4];
    for (int ni = 0; ni < 4; ni++)
        bv[ni] = bias[(size_t)e * DIM + n0 + wave_n + ni * 16 + lane15];
    for (int mi = 0; mi < 4; mi++) {
        for (int r = 0; r < 4; r++) {
            int rl = wave_m + mi * 16 + quad * 4 + r;
            if (rl < valid) {
                int orig = rowmap[pos0 + rl];
                size_t rb = (size_t)orig * DIM;
                for (int ni = 0; ni < 4; ni++) {
                    int col = n0 + wave_n + ni * 16 + lane15;
                    float v = acc[mi][ni][r] + bv[ni];
                    v = v > 0.f ? v : 0.f;
                    out[rb + col] = x[rb + col] + v;
                }
            }
        }
    }
}

// slow-but-correct fallback if workspace is too small
__global__ void k_naive(const float* __restrict__ x, const int* __restrict__ ids,
                        const float* __restrict__ W, const float* __restrict__ b,
                        float* __restrict__ out) {
    __shared__ float lx[DIM];
    int i = blockIdx.x;
    for (int t = threadIdx.x; t < DIM; t += blockDim.x) lx[t] = x[(size_t)i * DIM + t];
    __syncthreads();
    int e = ids[i];
    const float* We = W + (size_t)e * DIM * DIM;
    for (int n = threadIdx.x; n < DIM; n += blockDim.x) {
        const float* wr = We + (size_t)n * DIM;
        float acc = 0.f;
        for (int k = 0; k < DIM; k += 4) {
            float4 w4 = *(const float4*)(wr + k);
            acc += lx[k] * w4.x + lx[k + 1] * w4.y + lx[k + 2] * w4.z + lx[k + 3] * w4.w;
        }
        float v = acc + b[(size_t)e * DIM + n];
        v = v > 0.f ? v : 0.f;
        out[(size_t)i * DIM + n] = lx[n] + v;
    }
}

extern "C" void kernel_launch(void* const* d_in, const int* in_sizes, int n_in,
                              void* d_out, int out_size, void* d_ws, size_t ws_size,
                              hipStream_t stream) {
    const float* x   = (const float*)d_in[0];
    const int*   ids = (const int*)d_in[1];
    const float* W   = (const float*)d_in[2];
    const float* b   = (const float*)d_in[3];
    float* out = (float*)d_out;

    if (ws_size < WS_NEED) {
        k_naive<<<BATCH, 256, 0, stream>>>(x, ids, W, b, out);
        return;
    }

    char* wsb = (char*)d_ws;
    int*  wsi = (int*)wsb;
    unsigned short* xg = (unsigned short*)(wsb + XG_BYTE_OFF);
    unsigned short* Wb = (unsigned short*)(wsb + WB_BYTE_OFF);
    int* rowmap = wsi + 512;

    k_init<<<1, 512, 0, stream>>>(wsi);
    k_hist<<<BATCH / 256, 256, 0, stream>>>(ids, wsi);
    k_plan<<<1, 1, 0, stream>>>(wsi);
    k_zeropad<<<NEXP, 256, 0, stream>>>(wsi, xg);
    k_cvtW<<<(NEXP * DIM * DIM / 8) / 256, 256, 0, stream>>>((const float4*)W, (uint4*)Wb);
    k_gather<<<BATCH, 256, 0, stream>>>(x, ids, wsi, xg, rowmap);

    dim3 g(DIM / BN, MAX_TILES);
    k_gemm<<<g, 256, 0, stream>>>(xg, Wb, x, b, wsi, rowmap, out);
}

// Round 2
// 501.731 us; speedup vs baseline: 1.0111x; 1.0111x over previous
//
#include <hip/hip_runtime.h>
#include <hip/hip_bf16.h>
#include <stdint.h>

#define BATCH 8192
#define DIM   2048
#define NEXP  8
#define BM    128
#define BN    256      // N per block (4 waves x 64)
#define BK    32
#define MAX_TILES 72
#define NBLK  (DIM / BN)   // 8

typedef __bf16 bf16x8 __attribute__((ext_vector_type(8)));
typedef float  f32x4  __attribute__((ext_vector_type(4)));

// ---- workspace layout ----
// counts   @ int 0    (8)
// cursor   @ int 16   (8)
// seg_start@ int 32   (8)
// ntiles   @ int 48
// tileExp  @ int 64   (96)
// tilePos0 @ int 160  (96)
// tileVal  @ int 256  (96)
// rowmap   @ int 512  (9216)
// xg  (bf16) @ byte 40960      : 9216*2048*2
// Wb  (bf16) @ byte 37,789,696 : 8*2048*2048*2
#define XG_BYTE_OFF 40960ull
#define WB_BYTE_OFF 37789696ull
#define WS_NEED     104898560ull

#define AS1(p) ((const __attribute__((address_space(1))) void*)(p))
#define AS3(p) ((__attribute__((address_space(3))) void*)(p))

__device__ __forceinline__ unsigned f2bf2(float lo, float hi) {
    unsigned ul = __float_as_uint(lo), uh = __float_as_uint(hi);
    ul = (ul + 0x7FFFu + ((ul >> 16) & 1u)) >> 16;   // RNE
    uh = (uh + 0x7FFFu + ((uh >> 16) & 1u)) >> 16;
    return (uh << 16) | ul;
}

// one dispatch: LDS histogram of ids + serial segment/tile plan
__global__ void k_plan(const int* __restrict__ ids, int* __restrict__ ws) {
    __shared__ int sc[NEXP];
    int t = threadIdx.x;
    if (t < NEXP) sc[t] = 0;
    __syncthreads();
    for (int i = t; i < BATCH; i += 256) atomicAdd(&sc[ids[i]], 1);
    __syncthreads();
    if (t == 0) {
        int pos = 0, mt = 0;
        for (int e = 0; e < NEXP; e++) {
            int c = sc[e];
            ws[e]      = c;    // counts
            ws[16 + e] = 0;    // cursor
            ws[32 + e] = pos;  // seg start
            int ntl = (c + BM - 1) / BM;
            for (int tt = 0; tt < ntl; tt++) {
                ws[64  + mt] = e;
                ws[160 + mt] = pos + tt * BM;
                int v = c - tt * BM;
                ws[256 + mt] = v < BM ? v : BM;
                mt++;
            }
            pos += ntl * BM;
        }
        ws[48] = mt;
    }
}

// fp32 W -> bf16, 8 elems/thread
__global__ void k_cvtW(const float4* __restrict__ W, uint4* __restrict__ Wb) {
    size_t i = (size_t)blockIdx.x * blockDim.x + threadIdx.x;
    float4 a = W[i * 2], b4 = W[i * 2 + 1];
    uint4 o;
    o.x = f2bf2(a.x, a.y);  o.y = f2bf2(a.z, a.w);
    o.z = f2bf2(b4.x, b4.y); o.w = f2bf2(b4.z, b4.w);
    Wb[i] = o;
}

// blocks [0,BATCH): claim slot, convert+copy row into xg, record rowmap
// blocks [BATCH, BATCH+1024): zero the padding rows (plan data already written)
__global__ void k_gather(const float* __restrict__ x, const int* __restrict__ ids,
                         int* __restrict__ ws, unsigned short* __restrict__ xg,
                         int* __restrict__ rowmap) {
    int b = blockIdx.x;
    if (b >= BATCH) {
        int p = b - BATCH;
        int row = -1;
        for (int e = 0; e < NEXP; e++) {
            int c = ws[e];
            int pe = ((c + BM - 1) & ~(BM - 1)) - c;
            if (p < pe) { row = ws[32 + e] + c + p; break; }
            p -= pe;
        }
        if (row < 0) return;
        uint4* o = (uint4*)(xg + (size_t)row * DIM);
        uint4 z = make_uint4(0, 0, 0, 0);
        for (int t = threadIdx.x; t < DIM / 8; t += 256) o[t] = z;
        return;
    }
    __shared__ int spos;
    if (threadIdx.x == 0) {
        int e = ids[b];
        int p = ws[32 + e] + atomicAdd(&ws[16 + e], 1);
        spos = p;
        rowmap[p] = b;
    }
    __syncthreads();
    int pos = spos;
    const float4* xr = (const float4*)(x + (size_t)b * DIM);
    uint4* o = (uint4*)(xg + (size_t)pos * DIM);
    for (int t = threadIdx.x; t < DIM / 8; t += 256) {
        float4 a = xr[t * 2], b4 = xr[t * 2 + 1];
        uint4 v;
        v.x = f2bf2(a.x, a.y);  v.y = f2bf2(a.z, a.w);
        v.z = f2bf2(b4.x, b4.y); v.w = f2bf2(b4.z, b4.w);
        o[t] = v;
    }
}

// grouped GEMM: tile 128(M) x 256(N), 4 waves, wave-tile 128x64 (8x4 frags).
// FLOP/LDS-byte = 42.7 (vs 32 for 64x64 wave-tile).
__launch_bounds__(256, 2)
__global__ void k_gemm(const unsigned short* __restrict__ xg,
                       const unsigned short* __restrict__ Wb,
                       const float* __restrict__ x, const float* __restrict__ bias,
                       const int* __restrict__ ws, const int* __restrict__ rowmap,
                       float* __restrict__ out) {
    int mt = blockIdx.y;
    if (mt >= ws[48]) return;
    int e     = ws[64  + mt];
    int pos0  = ws[160 + mt];
    int valid = ws[256 + mt];
    int n0 = blockIdx.x * BN;

    __shared__ unsigned short lA[BM * BK];  // 8 KB
    __shared__ unsigned short lB[BN * BK];  // 16 KB

    int tid = threadIdx.x;
    int w = tid >> 6, l = tid & 63;
    int lane15 = l & 15, quad = l >> 4;
    int wave_n = w * 64;

    const unsigned short* Abase = xg + (size_t)pos0 * DIM;
    const unsigned short* Bbase = Wb + (size_t)e * DIM * DIM + (size_t)n0 * DIM;

    f32x4 acc[8][4];
#pragma unroll
    for (int i = 0; i < 8; i++)
#pragma unroll
        for (int j = 0; j < 4; j++) acc[i][j] = (f32x4){0.f, 0.f, 0.f, 0.f};

    for (int k0 = 0; k0 < DIM; k0 += BK) {
        __syncthreads();
        // A: 512 chunks of 16B; wave w stages chunks w*128 + j*64 + l, j=0,1
#pragma unroll
        for (int j = 0; j < 2; j++) {
            int c = w * 128 + j * 64 + l;
            __builtin_amdgcn_global_load_lds(
                AS1(Abase + (size_t)(c >> 2) * DIM + k0 + (c & 3) * 8),
                AS3(lA + w * 1024 + j * 512), 16, 0, 0);
        }
        // B: 1024 chunks; wave w stages chunks w*256 + j*64 + l, j=0..3
#pragma unroll
        for (int j = 0; j < 4; j++) {
            int c = w * 256 + j * 64 + l;
            __builtin_amdgcn_global_load_lds(
                AS1(Bbase + (size_t)(c >> 2) * DIM + k0 + (c & 3) * 8),
                AS3(lB + w * 2048 + j * 512), 16, 0, 0);
        }
        __syncthreads();

        bf16x8 af[8], bf[4];
#pragma unroll
        for (int mi = 0; mi < 8; mi++)
            af[mi] = *(const bf16x8*)(lA + (mi * 16 + lane15) * BK + quad * 8);
#pragma unroll
        for (int ni = 0; ni < 4; ni++)
            bf[ni] = *(const bf16x8*)(lB + (wave_n + ni * 16 + lane15) * BK + quad * 8);
#pragma unroll
        for (int mi = 0; mi < 8; mi++)
#pragma unroll
            for (int ni = 0; ni < 4; ni++)
                acc[mi][ni] = __builtin_amdgcn_mfma_f32_16x16x32_bf16(
                    af[mi], bf[ni], acc[mi][ni], 0, 0, 0);
    }

    // epilogue: bias + relu + residual + scatter via rowmap
    float bv[4];
#pragma unroll
    for (int ni = 0; ni < 4; ni++)
        bv[ni] = bias[(size_t)e * DIM + n0 + wave_n + ni * 16 + lane15];
#pragma unroll
    for (int mi = 0; mi < 8; mi++) {
#pragma unroll
        for (int r = 0; r < 4; r++) {
            int rl = mi * 16 + quad * 4 + r;
            if (rl < valid) {
                int orig = rowmap[pos0 + rl];
                size_t rb = (size_t)orig * DIM;
#pragma unroll
                for (int ni = 0; ni < 4; ni++) {
                    int col = n0 + wave_n + ni * 16 + lane15;
                    float v = acc[mi][ni][r] + bv[ni];
                    v = v > 0.f ? v : 0.f;
                    out[rb + col] = x[rb + col] + v;
                }
            }
        }
    }
}

// slow-but-correct fallback if workspace is too small
__global__ void k_naive(const float* __restrict__ x, const int* __restrict__ ids,
                        const float* __restrict__ W, const float* __restrict__ b,
                        float* __restrict__ out) {
    __shared__ float lx[DIM];
    int i = blockIdx.x;
    for (int t = threadIdx.x; t < DIM; t += blockDim.x) lx[t] = x[(size_t)i * DIM + t];
    __syncthreads();
    int e = ids[i];
    const float* We = W + (size_t)e * DIM * DIM;
    for (int n = threadIdx.x; n < DIM; n += blockDim.x) {
        const float* wr = We + (size_t)n * DIM;
        float acc = 0.f;
        for (int k = 0; k < DIM; k += 4) {
            float4 w4 = *(const float4*)(wr + k);
            acc += lx[k] * w4.x + lx[k + 1] * w4.y + lx[k + 2] * w4.z + lx[k + 3] * w4.w;
        }
        float v = acc + b[(size_t)e * DIM + n];
        v = v > 0.f ? v : 0.f;
        out[(size_t)i * DIM + n] = lx[n] + v;
    }
}

extern "C" void kernel_launch(void* const* d_in, const int* in_sizes, int n_in,
                              void* d_out, int out_size, void* d_ws, size_t ws_size,
                              hipStream_t stream) {
    const float* x   = (const float*)d_in[0];
    const int*   ids = (const int*)d_in[1];
    const float* W   = (const float*)d_in[2];
    const float* b   = (const float*)d_in[3];
    float* out = (float*)d_out;

    if (ws_size < WS_NEED) {
        k_naive<<<BATCH, 256, 0, stream>>>(x, ids, W, b, out);
        return;
    }

    char* wsb = (char*)d_ws;
    int*  wsi = (int*)wsb;
    unsigned short* xg = (unsigned short*)(wsb + XG_BYTE_OFF);
    unsigned short* Wb = (unsigned short*)(wsb + WB_BYTE_OFF);
    int* rowmap = wsi + 512;

    k_plan<<<1, 256, 0, stream>>>(ids, wsi);
    k_cvtW<<<(NEXP * DIM * DIM / 8) / 256, 256, 0, stream>>>((const float4*)W, (uint4*)Wb);
    k_gather<<<BATCH + 1024, 256, 0, stream>>>(x, ids, wsi, xg, rowmap);

    dim3 g(NBLK, MAX_TILES);
    k_gemm<<<g, 256, 0, stream>>>(xg, Wb, x, b, wsi, rowmap, out);
}

// Round 3
// 462.427 us; speedup vs baseline: 1.0971x; 1.0850x over previous
//
#include <hip/hip_runtime.h>
#include <hip/hip_bf16.h>
#include <stdint.h>

#define BATCH 8192
#define DIM   2048
#define NEXP  8
#define BM    128
#define BN    128
#define BK    64
#define MAX_TILES 72
#define NBLK  (DIM / BN)   // 16

typedef __bf16 bf16x8 __attribute__((ext_vector_type(8)));
typedef float  f32x4  __attribute__((ext_vector_type(4)));

// ---- workspace layout ----
// counts@0(8) cursor@16(8) seg@32(8) ntiles@48 tileExp@64(96) tilePos0@160(96)
// tileVal@256(96) rowmap@512(9216)
// xg (bf16) @ byte 40960 ; Wb (bf16) @ byte 37,789,696
#define XG_BYTE_OFF 40960ull
#define WB_BYTE_OFF 37789696ull
#define WS_NEED     104898560ull

#define AS1(p) ((const __attribute__((address_space(1))) void*)(p))
#define AS3(p) ((__attribute__((address_space(3))) void*)(p))

__device__ __forceinline__ unsigned f2bf2(float lo, float hi) {
    unsigned ul = __float_as_uint(lo), uh = __float_as_uint(hi);
    ul = (ul + 0x7FFFu + ((ul >> 16) & 1u)) >> 16;   // RNE
    uh = (uh + 0x7FFFu + ((uh >> 16) & 1u)) >> 16;
    return (uh << 16) | ul;
}

// one dispatch: LDS histogram of ids + serial segment/tile plan
__global__ void k_plan(const int* __restrict__ ids, int* __restrict__ ws) {
    __shared__ int sc[NEXP];
    int t = threadIdx.x;
    if (t < NEXP) sc[t] = 0;
    __syncthreads();
    for (int i = t; i < BATCH; i += 256) atomicAdd(&sc[ids[i]], 1);
    __syncthreads();
    if (t == 0) {
        int pos = 0, mt = 0;
        for (int e = 0; e < NEXP; e++) {
            int c = sc[e];
            ws[e]      = c;
            ws[16 + e] = 0;
            ws[32 + e] = pos;
            int ntl = (c + BM - 1) / BM;
            for (int tt = 0; tt < ntl; tt++) {
                ws[64  + mt] = e;
                ws[160 + mt] = pos + tt * BM;
                int v = c - tt * BM;
                ws[256 + mt] = v < BM ? v : BM;
                mt++;
            }
            pos += ntl * BM;
        }
        ws[48] = mt;
    }
}

// fp32 W -> bf16, 4 elems/thread, coalesced 16B-in / 8B-out
__global__ void k_cvtW(const float4* __restrict__ W, uint2* __restrict__ Wb) {
    size_t i = (size_t)blockIdx.x * blockDim.x + threadIdx.x;
    float4 a = W[i];
    uint2 o;
    o.x = f2bf2(a.x, a.y);
    o.y = f2bf2(a.z, a.w);
    Wb[i] = o;
}

// blocks [0,BATCH): claim slot, convert+copy row into xg, record rowmap
// blocks [BATCH, BATCH+1024): zero padding rows
__global__ void k_gather(const float* __restrict__ x, const int* __restrict__ ids,
                         int* __restrict__ ws, unsigned short* __restrict__ xg,
                         int* __restrict__ rowmap) {
    int b = blockIdx.x;
    if (b >= BATCH) {
        int p = b - BATCH;
        int row = -1;
        for (int e = 0; e < NEXP; e++) {
            int c = ws[e];
            int pe = ((c + BM - 1) & ~(BM - 1)) - c;
            if (p < pe) { row = ws[32 + e] + c + p; break; }
            p -= pe;
        }
        if (row < 0) return;
        uint4* o = (uint4*)(xg + (size_t)row * DIM);
        uint4 z = make_uint4(0, 0, 0, 0);
        for (int t = threadIdx.x; t < DIM / 8; t += 256) o[t] = z;
        return;
    }
    __shared__ int spos;
    if (threadIdx.x == 0) {
        int e = ids[b];
        int p = ws[32 + e] + atomicAdd(&ws[16 + e], 1);
        spos = p;
        rowmap[p] = b;
    }
    __syncthreads();
    int pos = spos;
    const float4* xr = (const float4*)(x + (size_t)b * DIM);
    uint4* o = (uint4*)(xg + (size_t)pos * DIM);
    for (int t = threadIdx.x; t < DIM / 8; t += 256) {
        float4 a = xr[t * 2], b4 = xr[t * 2 + 1];
        uint4 v;
        v.x = f2bf2(a.x, a.y);  v.y = f2bf2(a.z, a.w);
        v.z = f2bf2(b4.x, b4.y); v.w = f2bf2(b4.z, b4.w);
        o[t] = v;
    }
}

// grouped GEMM: 128x128 tile, 4 waves (2x2 of 64x64), BK=64,
// XOR-swizzled LDS (conflict-free ds_read_b128), global_load_lds(16B) staging.
// LDS row = BK shorts = 128B = 8 chunks of 16B; logical chunk q of row r is
// stored at position q ^ (r&7)  (swizzle applied to the STAGING SOURCE addr,
// keeping the wave-uniform-dest constraint of global_load_lds).
__launch_bounds__(256)
__global__ void k_gemm(const unsigned short* __restrict__ xg,
                       const unsigned short* __restrict__ Wb,
                       const float* __restrict__ x, const float* __restrict__ bias,
                       const int* __restrict__ ws, const int* __restrict__ rowmap,
                       float* __restrict__ out) {
    int mt = blockIdx.y;
    if (mt >= ws[48]) return;
    int e     = ws[64  + mt];
    int pos0  = ws[160 + mt];
    int valid = ws[256 + mt];
    int n0 = blockIdx.x * BN;

    __shared__ unsigned short lA[BM * BK];  // 16 KB
    __shared__ unsigned short lB[BN * BK];  // 16 KB

    int tid = threadIdx.x;
    int w = tid >> 6, l = tid & 63;
    int lane15 = l & 15, quad = l >> 4;
    int wave_m = (w >> 1) * 64, wave_n = (w & 1) * 64;

    const unsigned short* Abase = xg + (size_t)pos0 * DIM;
    const unsigned short* Bbase = Wb + (size_t)e * DIM * DIM + (size_t)n0 * DIM;

    f32x4 acc[4][4];
#pragma unroll
    for (int i = 0; i < 4; i++)
#pragma unroll
        for (int j = 0; j < 4; j++) acc[i][j] = (f32x4){0.f, 0.f, 0.f, 0.f};

    // staging: 1024 chunks of 16B per tile side; wave w takes chunks
    // [w*256, w*256+256) in 4 issues of 64. chunk c -> row=c>>3, pos=c&7,
    // logical k-chunk q = pos ^ (row&7).
    int src_row[4], src_q[4];
#pragma unroll
    for (int j = 0; j < 4; j++) {
        int c = w * 256 + j * 64 + l;
        src_row[j] = c >> 3;
        src_q[j] = (c & 7) ^ (src_row[j] & 7);
    }

    for (int k0 = 0; k0 < DIM; k0 += BK) {
        __syncthreads();
#pragma unroll
        for (int j = 0; j < 4; j++) {
            __builtin_amdgcn_global_load_lds(
                AS1(Abase + (size_t)src_row[j] * DIM + k0 + src_q[j] * 8),
                AS3(lA + (w * 256 + j * 64) * 8), 16, 0, 0);
        }
#pragma unroll
        for (int j = 0; j < 4; j++) {
            __builtin_amdgcn_global_load_lds(
                AS1(Bbase + (size_t)src_row[j] * DIM + k0 + src_q[j] * 8),
                AS3(lB + (w * 256 + j * 64) * 8), 16, 0, 0);
        }
        __syncthreads();

#pragma unroll
        for (int s = 0; s < 2; s++) {
            bf16x8 af[4], bf[4];
            int q = s * 4 + quad;
#pragma unroll
            for (int mi = 0; mi < 4; mi++) {
                int r = wave_m + mi * 16 + lane15;
                af[mi] = *(const bf16x8*)(lA + r * BK + ((q ^ (r & 7)) * 8));
            }
#pragma unroll
            for (int ni = 0; ni < 4; ni++) {
                int r = wave_n + ni * 16 + lane15;
                bf[ni] = *(const bf16x8*)(lB + r * BK + ((q ^ (r & 7)) * 8));
            }
#pragma unroll
            for (int mi = 0; mi < 4; mi++)
#pragma unroll
                for (int ni = 0; ni < 4; ni++)
                    acc[mi][ni] = __builtin_amdgcn_mfma_f32_16x16x32_bf16(
                        af[mi], bf[ni], acc[mi][ni], 0, 0, 0);
        }
    }

    // epilogue: bias + relu + residual + scatter via rowmap
    float bv[4];
#pragma unroll
    for (int ni = 0; ni < 4; ni++)
        bv[ni] = bias[(size_t)e * DIM + n0 + wave_n + ni * 16 + lane15];
#pragma unroll
    for (int mi = 0; mi < 4; mi++) {
#pragma unroll
        for (int r = 0; r < 4; r++) {
            int rl = wave_m + mi * 16 + quad * 4 + r;
            if (rl < valid) {
                int orig = rowmap[pos0 + rl];
                size_t rb = (size_t)orig * DIM;
#pragma unroll
                for (int ni = 0; ni < 4; ni++) {
                    int col = n0 + wave_n + ni * 16 + lane15;
                    float v = acc[mi][ni][r] + bv[ni];
                    v = v > 0.f ? v : 0.f;
                    out[rb + col] = x[rb + col] + v;
                }
            }
        }
    }
}

// slow-but-correct fallback if workspace is too small
__global__ void k_naive(const float* __restrict__ x, const int* __restrict__ ids,
                        const float* __restrict__ W, const float* __restrict__ b,
                        float* __restrict__ out) {
    __shared__ float lx[DIM];
    int i = blockIdx.x;
    for (int t = threadIdx.x; t < DIM; t += blockDim.x) lx[t] = x[(size_t)i * DIM + t];
    __syncthreads();
    int e = ids[i];
    const float* We = W + (size_t)e * DIM * DIM;
    for (int n = threadIdx.x; n < DIM; n += blockDim.x) {
        const float* wr = We + (size_t)n * DIM;
        float acc = 0.f;
        for (int k = 0; k < DIM; k += 4) {
            float4 w4 = *(const float4*)(wr + k);
            acc += lx[k] * w4.x + lx[k + 1] * w4.y + lx[k + 2] * w4.z + lx[k + 3] * w4.w;
        }
        float v = acc + b[(size_t)e * DIM + n];
        v = v > 0.f ? v : 0.f;
        out[(size_t)i * DIM + n] = lx[n] + v;
    }
}

extern "C" void kernel_launch(void* const* d_in, const int* in_sizes, int n_in,
                              void* d_out, int out_size, void* d_ws, size_t ws_size,
                              hipStream_t stream) {
    const float* x   = (const float*)d_in[0];
    const int*   ids = (const int*)d_in[1];
    const float* W   = (const float*)d_in[2];
    const float* b   = (const float*)d_in[3];
    float* out = (float*)d_out;

    if (ws_size < WS_NEED) {
        k_naive<<<BATCH, 256, 0, stream>>>(x, ids, W, b, out);
        return;
    }

    char* wsb = (char*)d_ws;
    int*  wsi = (int*)wsb;
    unsigned short* xg = (unsigned short*)(wsb + XG_BYTE_OFF);
    unsigned short* Wb = (unsigned short*)(wsb + WB_BYTE_OFF);
    int* rowmap = wsi + 512;

    k_plan<<<1, 256, 0, stream>>>(ids, wsi);
    k_cvtW<<<(NEXP * DIM * DIM / 4) / 256, 256, 0, stream>>>((const float4*)W, (uint2*)Wb);
    k_gather<<<BATCH + 1024, 256, 0, stream>>>(x, ids, wsi, xg, rowmap);

    dim3 g(NBLK, MAX_TILES);
    k_gemm<<<g, 256, 0, stream>>>(xg, Wb, x, b, wsi, rowmap, out);
}

// Round 4
// 460.971 us; speedup vs baseline: 1.1005x; 1.0032x over previous
//
#include <hip/hip_runtime.h>
#include <hip/hip_bf16.h>
#include <stdint.h>

#define BATCH 8192
#define DIM   2048
#define NEXP  8
#define BM    128
#define BN    128
#define BK    32
#define NITER (DIM / BK)   // 64
#define MAX_TILES 72
#define NBLK  (DIM / BN)   // 16

typedef __bf16 bf16x8 __attribute__((ext_vector_type(8)));
typedef float  f32x4  __attribute__((ext_vector_type(4)));

// ---- workspace layout ----
// counts@0(8) cursor@16(8) seg@32(8) ntiles@48 tileExp@64(96) tilePos0@160(96)
// tileVal@256(96) rowmap@512(9216)
// xg (bf16) @ byte 40960 ; Wb (bf16) @ byte 37,789,696
#define XG_BYTE_OFF 40960ull
#define WB_BYTE_OFF 37789696ull
#define WS_NEED     104898560ull

#define AS1(p) ((const __attribute__((address_space(1))) void*)(p))
#define AS3(p) ((__attribute__((address_space(3))) void*)(p))

__device__ __forceinline__ unsigned f2bf2(float lo, float hi) {
    unsigned ul = __float_as_uint(lo), uh = __float_as_uint(hi);
    ul = (ul + 0x7FFFu + ((ul >> 16) & 1u)) >> 16;   // RNE
    uh = (uh + 0x7FFFu + ((uh >> 16) & 1u)) >> 16;
    return (uh << 16) | ul;
}

// one dispatch: LDS histogram of ids + serial segment/tile plan
__global__ void k_plan(const int* __restrict__ ids, int* __restrict__ ws) {
    __shared__ int sc[NEXP];
    int t = threadIdx.x;
    if (t < NEXP) sc[t] = 0;
    __syncthreads();
    for (int i = t; i < BATCH; i += 256) atomicAdd(&sc[ids[i]], 1);
    __syncthreads();
    if (t == 0) {
        int pos = 0, mt = 0;
        for (int e = 0; e < NEXP; e++) {
            int c = sc[e];
            ws[e]      = c;
            ws[16 + e] = 0;
            ws[32 + e] = pos;
            int ntl = (c + BM - 1) / BM;
            for (int tt = 0; tt < ntl; tt++) {
                ws[64  + mt] = e;
                ws[160 + mt] = pos + tt * BM;
                int v = c - tt * BM;
                ws[256 + mt] = v < BM ? v : BM;
                mt++;
            }
            pos += ntl * BM;
        }
        ws[48] = mt;
    }
}

// fp32 W -> bf16, 4 elems/thread, coalesced 16B-in / 8B-out
__global__ void k_cvtW(const float4* __restrict__ W, uint2* __restrict__ Wb) {
    size_t i = (size_t)blockIdx.x * blockDim.x + threadIdx.x;
    float4 a = W[i];
    uint2 o;
    o.x = f2bf2(a.x, a.y);
    o.y = f2bf2(a.z, a.w);
    Wb[i] = o;
}

// blocks [0,BATCH): claim slot, convert+copy row into xg, record rowmap
// blocks [BATCH, BATCH+1024): zero padding rows
__global__ void k_gather(const float* __restrict__ x, const int* __restrict__ ids,
                         int* __restrict__ ws, unsigned short* __restrict__ xg,
                         int* __restrict__ rowmap) {
    int b = blockIdx.x;
    if (b >= BATCH) {
        int p = b - BATCH;
        int row = -1;
        for (int e = 0; e < NEXP; e++) {
            int c = ws[e];
            int pe = ((c + BM - 1) & ~(BM - 1)) - c;
            if (p < pe) { row = ws[32 + e] + c + p; break; }
            p -= pe;
        }
        if (row < 0) return;
        uint4* o = (uint4*)(xg + (size_t)row * DIM);
        uint4 z = make_uint4(0, 0, 0, 0);
        for (int t = threadIdx.x; t < DIM / 8; t += 256) o[t] = z;
        return;
    }
    __shared__ int spos;
    if (threadIdx.x == 0) {
        int e = ids[b];
        int p = ws[32 + e] + atomicAdd(&ws[16 + e], 1);
        spos = p;
        rowmap[p] = b;
    }
    __syncthreads();
    int pos = spos;
    const float4* xr = (const float4*)(x + (size_t)b * DIM);
    uint4* o = (uint4*)(xg + (size_t)pos * DIM);
    for (int t = threadIdx.x; t < DIM / 8; t += 256) {
        float4 a = xr[t * 2], b4 = xr[t * 2 + 1];
        uint4 v;
        v.x = f2bf2(a.x, a.y);  v.y = f2bf2(a.z, a.w);
        v.z = f2bf2(b4.x, b4.y); v.w = f2bf2(b4.z, b4.w);
        o[t] = v;
    }
}

// grouped GEMM: 128x128 tile, 4 waves (2x2 of 64x64), BK=32,
// DOUBLE-BUFFERED LDS: single barrier per iter; prefetch tile i+1 while
// computing tile i (safe: barrier(i) proves all waves finished compute(i-1),
// so buf[(i+1)&1] = buf[(i-1)&1] is free to overwrite).
// Swizzle: 16B chunk at LDS position p of row r holds logical chunk
// p ^ ((r>>1)&3)  -> 2-way (free) bank aliasing on ds_read_b128 phases.
// Applied to the STAGING SOURCE address (dest stays wave-uniform contiguous).
__launch_bounds__(256)
__global__ void k_gemm(const unsigned short* __restrict__ xg,
                       const unsigned short* __restrict__ Wb,
                       const float* __restrict__ bias,
                       const int* __restrict__ ws, const int* __restrict__ rowmap,
                       float* __restrict__ out) {
    int mt = blockIdx.y;
    if (mt >= ws[48]) return;
    int e     = ws[64  + mt];
    int pos0  = ws[160 + mt];
    int valid = ws[256 + mt];
    int n0 = blockIdx.x * BN;

    __shared__ unsigned short lds[2][8192];  // [buf][0..4095]=A, [4096..8191]=B; 32 KB

    int tid = threadIdx.x;
    int w = tid >> 6, l = tid & 63;
    int lane15 = l & 15, quad = l >> 4;
    int wave_m = (w >> 1) * 64, wave_n = (w & 1) * 64;

    const unsigned short* Abase = xg + (size_t)pos0 * DIM;
    const unsigned short* Bbase = Wb + (size_t)e * DIM * DIM + (size_t)n0 * DIM;

    // staging source offsets (shorts), invariant across K except +k0.
    // tile side = 512 chunks of 16B; wave w stages chunks [w*128, w*128+128)
    // in 2 issues of 64. chunk c: row=c>>2, dest pos=c&3, src q = pos^((row>>1)&3)
    int srcOff[2];
#pragma unroll
    for (int j = 0; j < 2; j++) {
        int c = w * 128 + j * 64 + l;
        int row = c >> 2, pos = c & 3;
        int q = pos ^ ((row >> 1) & 3);
        srcOff[j] = row * DIM + q * 8;
    }

    // fragment read offsets (shorts), loop-invariant.
    // reader wants logical chunk = quad at row r -> dest pos quad^((r>>1)&3);
    // (r>>1)&3 == (lane15>>1)&3 since wave_m/mi*16 contribute bits >=3 only.
    int swz = (quad ^ ((lane15 >> 1) & 3)) * 8;
    int afOff[4], bfOff[4];
#pragma unroll
    for (int mi = 0; mi < 4; mi++)
        afOff[mi] = (wave_m + mi * 16 + lane15) * BK + swz;
#pragma unroll
    for (int ni = 0; ni < 4; ni++)
        bfOff[ni] = 4096 + (wave_n + ni * 16 + lane15) * BK + swz;

    f32x4 acc[4][4];
#pragma unroll
    for (int i = 0; i < 4; i++)
#pragma unroll
        for (int j = 0; j < 4; j++) acc[i][j] = (f32x4){0.f, 0.f, 0.f, 0.f};

#define ISSUE(buf, k0)                                                          \
    do {                                                                        \
        _Pragma("unroll")                                                       \
        for (int j = 0; j < 2; j++) {                                           \
            __builtin_amdgcn_global_load_lds(                                   \
                AS1(Abase + (k0) + srcOff[j]),                                  \
                AS3(&lds[buf][w * 1024 + j * 512]), 16, 0, 0);                  \
            __builtin_amdgcn_global_load_lds(                                   \
                AS1(Bbase + (k0) + srcOff[j]),                                  \
                AS3(&lds[buf][4096 + w * 1024 + j * 512]), 16, 0, 0);           \
        }                                                                       \
    } while (0)

    ISSUE(0, 0);
    int cur = 0;
    for (int i = 0; i < NITER; ++i) {
        __syncthreads();   // drains vmcnt(0): loads(i) complete (in flight
                           // during compute(i-1)); all compute(i-1) done.
        if (i + 1 < NITER) {
            int k0n = (i + 1) * BK;
            ISSUE(cur ^ 1, k0n);
        }
        bf16x8 af[4], bf[4];
#pragma unroll
        for (int mi = 0; mi < 4; mi++)
            af[mi] = *(const bf16x8*)(&lds[cur][afOff[mi]]);
#pragma unroll
        for (int ni = 0; ni < 4; ni++)
            bf[ni] = *(const bf16x8*)(&lds[cur][bfOff[ni]]);
#pragma unroll
        for (int mi = 0; mi < 4; mi++)
#pragma unroll
            for (int ni = 0; ni < 4; ni++)
                acc[mi][ni] = __builtin_amdgcn_mfma_f32_16x16x32_bf16(
                    af[mi], bf[ni], acc[mi][ni], 0, 0, 0);
        cur ^= 1;
    }
#undef ISSUE

    // epilogue: bias + relu + residual(from xg, bf16, contiguous) + scatter
    float bv[4];
#pragma unroll
    for (int ni = 0; ni < 4; ni++)
        bv[ni] = bias[(size_t)e * DIM + n0 + wave_n + ni * 16 + lane15];
#pragma unroll
    for (int mi = 0; mi < 4; mi++) {
#pragma unroll
        for (int r = 0; r < 4; r++) {
            int rl = wave_m + mi * 16 + quad * 4 + r;
            if (rl < valid) {
                int orig = rowmap[pos0 + rl];
                const unsigned short* xrow = xg + (size_t)(pos0 + rl) * DIM + n0;
                float* orow = out + (size_t)orig * DIM + n0;
#pragma unroll
                for (int ni = 0; ni < 4; ni++) {
                    int col = wave_n + ni * 16 + lane15;
                    float xv = __uint_as_float((unsigned)xrow[col] << 16);
                    float v = acc[mi][ni][r] + bv[ni];
                    v = v > 0.f ? v : 0.f;
                    orow[col] = xv + v;
                }
            }
        }
    }
}

// slow-but-correct fallback if workspace is too small
__global__ void k_naive(const float* __restrict__ x, const int* __restrict__ ids,
                        const float* __restrict__ W, const float* __restrict__ b,
                        float* __restrict__ out) {
    __shared__ float lx[DIM];
    int i = blockIdx.x;
    for (int t = threadIdx.x; t < DIM; t += blockDim.x) lx[t] = x[(size_t)i * DIM + t];
    __syncthreads();
    int e = ids[i];
    const float* We = W + (size_t)e * DIM * DIM;
    for (int n = threadIdx.x; n < DIM; n += blockDim.x) {
        const float* wr = We + (size_t)n * DIM;
        float acc = 0.f;
        for (int k = 0; k < DIM; k += 4) {
            float4 w4 = *(const float4*)(wr + k);
            acc += lx[k] * w4.x + lx[k + 1] * w4.y + lx[k + 2] * w4.z + lx[k + 3] * w4.w;
        }
        float v = acc + b[(size_t)e * DIM + n];
        v = v > 0.f ? v : 0.f;
        out[(size_t)i * DIM + n] = lx[n] + v;
    }
}

extern "C" void kernel_launch(void* const* d_in, const int* in_sizes, int n_in,
                              void* d_out, int out_size, void* d_ws, size_t ws_size,
                              hipStream_t stream) {
    const float* x   = (const float*)d_in[0];
    const int*   ids = (const int*)d_in[1];
    const float* W   = (const float*)d_in[2];
    const float* b   = (const float*)d_in[3];
    float* out = (float*)d_out;

    if (ws_size < WS_NEED) {
        k_naive<<<BATCH, 256, 0, stream>>>(x, ids, W, b, out);
        return;
    }

    char* wsb = (char*)d_ws;
    int*  wsi = (int*)wsb;
    unsigned short* xg = (unsigned short*)(wsb + XG_BYTE_OFF);
    unsigned short* Wb = (unsigned short*)(wsb + WB_BYTE_OFF);
    int* rowmap = wsi + 512;

    k_plan<<<1, 256, 0, stream>>>(ids, wsi);
    k_cvtW<<<(NEXP * DIM * DIM / 4) / 256, 256, 0, stream>>>((const float4*)W, (uint2*)Wb);
    k_gather<<<BATCH + 1024, 256, 0, stream>>>(x, ids, wsi, xg, rowmap);

    dim3 g(NBLK, MAX_TILES);
    k_gemm<<<g, 256, 0, stream>>>(xg, Wb, b, wsi, rowmap, out);
}